// Round 8
// baseline (188.126 us; speedup 1.0000x reference)
//
#include <hip/hip_runtime.h>
#include <hip/hip_bf16.h>
#include <math.h>

#define NA 2048   // agents (2^11)
#define TT 20     // timesteps
#define KK 32     // neighbors
#define CC 32     // in channels
#define OO 64     // out channels / hidden
#define GG 256    // 4*OO gates
#define FSW 72    // feat_sh row stride in shorts (144B: +4 banks/row)

typedef __attribute__((ext_vector_type(8))) short short8;
typedef __attribute__((ext_vector_type(4))) float float4v;
typedef __attribute__((ext_vector_type(4))) unsigned uint4v;

__device__ __forceinline__ float fast_rcp(float x) {
    return __builtin_amdgcn_rcpf(x);
}
__device__ __forceinline__ float sigm(float x) {
    return fast_rcp(1.f + __expf(-x));
}
__device__ __forceinline__ float tanh_fast(float x) {
    return 1.f - 2.f * fast_rcp(1.f + __expf(2.f * x));
}
// bf16 RNE on raw bits (ties-to-even; NaN not expected here).
__device__ __forceinline__ unsigned cvt_rne(float f) {
    unsigned u = __float_as_uint(f);
    return (u + 0x7FFFu + ((u >> 16) & 1u)) >> 16;
}
__device__ __forceinline__ unsigned pack2(float a, float b) {
    return cvt_rne(a) | (cvt_rne(b) << 16);
}
__device__ __forceinline__ float bf_lo(unsigned u) {
    return __uint_as_float(u << 16);
}
__device__ __forceinline__ float bf_hi(unsigned u) {
    return __uint_as_float(u & 0xffff0000u);
}

// P[t][n][o] = sum_c x[n][t][c] * conv_w[o][c], stored bf16 (128B rows).
// Block 0 pre-converts w_ih/w_hh to bf16 and precomputes the folded gate
// bias (b_ih + b_hh + conv_b @ w_ih^T).
__global__ __launch_bounds__(256) void proj_kernel(
    const float* __restrict__ x, const float* __restrict__ conv_w,
    const float* __restrict__ conv_b, const float* __restrict__ w_ih,
    const float* __restrict__ w_hh, const float* __restrict__ b_ih,
    const float* __restrict__ b_hh,
    __hip_bfloat16* __restrict__ P, unsigned short* __restrict__ wihb,
    unsigned short* __restrict__ whhb, float* __restrict__ biasT)
{
    const int tid = threadIdx.x;
    if (blockIdx.x == 0) {   // prep block
        for (int e = tid; e < 4 * OO * OO; e += 256) {
            wihb[e] = (unsigned short)cvt_rne(w_ih[e]);
            whhb[e] = (unsigned short)cvt_rne(w_hh[e]);
        }
        float bj = b_ih[tid] + b_hh[tid];
        #pragma unroll
        for (int o = 0; o < OO; o += 4) {
            float4 cb = *(const float4*)(conv_b + o);
            float4 wr = *(const float4*)(w_ih + (size_t)tid * OO + o);
            bj = fmaf(cb.x, wr.x, bj); bj = fmaf(cb.y, wr.y, bj);
            bj = fmaf(cb.z, wr.z, bj); bj = fmaf(cb.w, wr.w, bj);
        }
        biasT[tid] = bj;
        return;
    }
    const int lane = tid & 63;
    const int wv = tid >> 6;
    float w[CC];
    #pragma unroll
    for (int c = 0; c < CC; c += 4) {
        float4 v = *(const float4*)(conv_w + lane * CC + c);
        w[c] = v.x; w[c + 1] = v.y; w[c + 2] = v.z; w[c + 3] = v.w;
    }
    const int rbase = (blockIdx.x - 1) * 16 + wv * 4;
    #pragma unroll
    for (int i = 0; i < 4; ++i) {
        int r = rbase + i;                    // r = n*TT + t (x row order)
        const float* xr = x + (size_t)r * CC;
        float a0 = 0.f, a1 = 0.f;
        #pragma unroll
        for (int c = 0; c < CC; c += 8) {
            float4 v = *(const float4*)(xr + c);
            float4 u = *(const float4*)(xr + c + 4);
            a0 = fmaf(v.x, w[c], a0);     a0 = fmaf(v.y, w[c + 1], a0);
            a0 = fmaf(v.z, w[c + 2], a0); a0 = fmaf(v.w, w[c + 3], a0);
            a1 = fmaf(u.x, w[c + 4], a1); a1 = fmaf(u.y, w[c + 5], a1);
            a1 = fmaf(u.z, w[c + 6], a1); a1 = fmaf(u.w, w[c + 7], a1);
        }
        int n = r / TT;
        int t = r - n * TT;
        ((unsigned short*)P)[(((size_t)t << 11) + n) * OO + lane] =
            (unsigned short)cvt_rne(a0 + a1);
    }
}

// Fused gather-max + gate MFMA, LDS-slab edition.
// R4-R6 post-mortem: the random 128B global gather is pinned at ~53us no
// matter how it's scheduled (per-CU miss-tracking limit). So: stream the
// 256KB t-slab through LDS in 2 passes of 1024 rows (coalesced loads +
// ds_write_b128) and do the random gather from LDS instead. Block = one
// (t, 128-agent chunk); thread owns (agent, 16B channel-chunk) and
// max-accumulates 32 neighbors across both passes in registers.
__global__ __launch_bounds__(256) void gfeat_kernel(
    const __hip_bfloat16* __restrict__ P, const int* __restrict__ A,
    const unsigned short* __restrict__ wihb, const float* __restrict__ biasT,
    __hip_bfloat16* __restrict__ gx)
{
    extern __shared__ __align__(16) unsigned short slab[];   // 1024*64 shorts
    __shared__ __align__(16) unsigned short feat_sh[128 * FSW];

    const int tid = threadIdx.x;
    const int lane = tid & 63;
    const int w = tid >> 6;

    const int t = blockIdx.x >> 4;          // 20 t-slabs
    const int n0 = (blockIdx.x & 15) << 7;  // 128 agents per chunk
    const unsigned short* Pt = (const unsigned short*)P + ((size_t)t << 17);

    const int a_loc = w * 8 + (lane >> 3);  // agent within 32-agent group
    const int c = lane & 7;                 // 16B chunk (8 channels)

    float mx[4][8];
    #pragma unroll
    for (int g = 0; g < 4; ++g)
        #pragma unroll
        for (int e = 0; e < 8; ++e) mx[g][e] = -INFINITY;

    for (int pass = 0; pass < 2; ++pass) {
        if (pass) __syncthreads();          // prior pass's reads done
        // ---- stage rows [pass*1024, +1024) : 128KB coalesced ----
        const unsigned short* src = Pt + (pass << 16);       // *65536 shorts
        #pragma unroll 4
        for (int it = 0; it < 32; ++it) {
            int off = (it * 256 + tid) * 8;                  // shorts
            uint4v v = *(const uint4v*)(src + off);
            *(uint4v*)(slab + off) = v;
        }
        __syncthreads();                    // slab visible

        // ---- gather-max from LDS ----
        const unsigned lo = pass << 10;
        #pragma unroll
        for (int g = 0; g < 4; ++g) {
            const int a = g * 32 + a_loc;   // 0..127
            const int* Arow = A + (((size_t)(t << 11) + n0 + a) << 5);
            #pragma unroll
            for (int k4 = 0; k4 < 8; ++k4) {
                int4 iv = ((const int4*)Arow)[k4];
                #pragma unroll
                for (int e4 = 0; e4 < 4; ++e4) {
                    int idx = (e4 == 0) ? iv.x : (e4 == 1) ? iv.y
                             : (e4 == 2) ? iv.z : iv.w;
                    unsigned rel = (unsigned)idx - lo;
                    if (rel < 1024u) {
                        uint4v v = *(const uint4v*)(slab + (rel << 6) + c * 8);
                        mx[g][0] = fmaxf(mx[g][0], bf_lo(v[0]));
                        mx[g][1] = fmaxf(mx[g][1], bf_hi(v[0]));
                        mx[g][2] = fmaxf(mx[g][2], bf_lo(v[1]));
                        mx[g][3] = fmaxf(mx[g][3], bf_hi(v[1]));
                        mx[g][4] = fmaxf(mx[g][4], bf_lo(v[2]));
                        mx[g][5] = fmaxf(mx[g][5], bf_hi(v[2]));
                        mx[g][6] = fmaxf(mx[g][6], bf_lo(v[3]));
                        mx[g][7] = fmaxf(mx[g][7], bf_hi(v[3]));
                    }
                }
            }
        }
    }

    // ---- self-subtract, write feat tile (separate static LDS) ----
    #pragma unroll
    for (int g = 0; g < 4; ++g) {
        const int a = g * 32 + a_loc;
        uint4v sv = *(const uint4v*)(Pt + (((size_t)(n0 + a)) << 6) + c * 8);
        uint4v pk;
        pk[0] = pack2(mx[g][0] - bf_lo(sv[0]), mx[g][1] - bf_hi(sv[0]));
        pk[1] = pack2(mx[g][2] - bf_lo(sv[1]), mx[g][3] - bf_hi(sv[1]));
        pk[2] = pack2(mx[g][4] - bf_lo(sv[2]), mx[g][5] - bf_hi(sv[2]));
        pk[3] = pack2(mx[g][6] - bf_lo(sv[3]), mx[g][7] - bf_hi(sv[3]));
        *(uint4v*)&feat_sh[a * FSW + c * 8] = pk;
    }
    __syncthreads();

    // ---- gate MFMA: 128 rows x 256 cols; wave w owns cols w*64..+63 ----
    const int l15 = lane & 15;
    const int q = lane >> 4;
    float bv[4];
    short8 bfrag[4][2];
    #pragma unroll
    for (int tt2 = 0; tt2 < 4; ++tt2) {
        int j = w * 64 + tt2 * 16 + l15;
        bv[tt2] = biasT[j];
        #pragma unroll
        for (int ks = 0; ks < 2; ++ks)
            bfrag[tt2][ks] =
                *(const short8*)(wihb + ((size_t)j << 6) + ks * 32 + q * 8);
    }
    unsigned short* gxp = (unsigned short*)gx;
    #pragma unroll
    for (int tile = 0; tile < 8; ++tile) {
        float4v acc[4] = {{0.f, 0.f, 0.f, 0.f}, {0.f, 0.f, 0.f, 0.f},
                          {0.f, 0.f, 0.f, 0.f}, {0.f, 0.f, 0.f, 0.f}};
        #pragma unroll
        for (int ks = 0; ks < 2; ++ks) {
            short8 af = *(const short8*)(
                &feat_sh[(tile * 16 + l15) * FSW + ks * 32 + q * 8]);
            #pragma unroll
            for (int tt2 = 0; tt2 < 4; ++tt2)
                acc[tt2] = __builtin_amdgcn_mfma_f32_16x16x32_bf16(
                    af, bfrag[tt2][ks], acc[tt2], 0, 0, 0);
        }
        const size_t rbase = (size_t)(t << 11) + n0 + tile * 16;
        #pragma unroll
        for (int tt2 = 0; tt2 < 4; ++tt2) {
            int j = w * 64 + tt2 * 16 + l15;
            #pragma unroll
            for (int rg = 0; rg < 4; ++rg)
                gxp[((rbase + q * 4 + rg) << 8) + j] =
                    (unsigned short)cvt_rne(acc[tt2][rg] + bv[tt2]);
        }
    }
}

// Serial recurrence via MFMA: 16 agents/block (128 blocks), R4/R5 structure
// (no junk rows — R6's 8-agent variant regressed) with preconverted whhb.
__global__ __launch_bounds__(256, 4) void lstm_kernel(
    const __hip_bfloat16* __restrict__ gx, const unsigned short* __restrict__ whhb,
    float* __restrict__ out)
{
    const int tid = threadIdx.x;
    const int lane = tid & 63;
    const int wv = tid >> 6;          // gate plane
    const int l15 = lane & 15;
    const int q = lane >> 4;
    const int a0 = blockIdx.x * 16;
    const int a = tid >> 4;           // pointwise: agent 0..15
    const int c0 = (tid & 15) * 4;    // pointwise: first channel

    // B-frags from preconverted bf16: B[k][ch] = w_hh[wv*64 + ch][k]
    short8 bfrag[4][2];
    #pragma unroll
    for (int tt2 = 0; tt2 < 4; ++tt2) {
        int row = wv * 64 + tt2 * 16 + l15;
        #pragma unroll
        for (int ks = 0; ks < 2; ++ks)
            bfrag[tt2][ks] =
                *(const short8*)(whhb + ((size_t)row << 6) + ks * 32 + q * 8);
    }

    __shared__ __align__(16) unsigned short h_sh[16 * 72];  // bf16, pad 72
    __shared__ float gp[4][16][68];                         // gate planes

    {   // h = 0
        uint2 z; z.x = 0u; z.y = 0u;
        *(uint2*)&h_sh[a * 72 + c0] = z;
    }
    float cst[4] = {0.f, 0.f, 0.f, 0.f};

    const unsigned short* gxp = (const unsigned short*)gx;
    uint2 gxv[4];
    #pragma unroll
    for (int g = 0; g < 4; ++g)
        gxv[g] = *(const uint2*)(gxp + ((size_t)(a0 + a) << 8) + g * 64 + c0);

    for (int t = 0; t < TT; ++t) {
        __syncthreads();  // h_sh ready (init or previous pointwise)

        float4v acc[4] = {{0.f, 0.f, 0.f, 0.f}, {0.f, 0.f, 0.f, 0.f},
                          {0.f, 0.f, 0.f, 0.f}, {0.f, 0.f, 0.f, 0.f}};
        #pragma unroll
        for (int ks = 0; ks < 2; ++ks) {
            short8 af = *(const short8*)(&h_sh[l15 * 72 + ks * 32 + q * 8]);
            #pragma unroll
            for (int tt2 = 0; tt2 < 4; ++tt2)
                acc[tt2] = __builtin_amdgcn_mfma_f32_16x16x32_bf16(
                    af, bfrag[tt2][ks], acc[tt2], 0, 0, 0);
        }
        #pragma unroll
        for (int tt2 = 0; tt2 < 4; ++tt2)
            #pragma unroll
            for (int rg = 0; rg < 4; ++rg)
                gp[wv][q * 4 + rg][tt2 * 16 + l15] = acc[tt2][rg];

        // prefetch next step's gx while gp settles
        uint2 gxn[4];
        int tn = (t + 1 < TT) ? t + 1 : t;
        #pragma unroll
        for (int g = 0; g < 4; ++g)
            gxn[g] = *(const uint2*)(gxp + (((size_t)tn << 11) + a0 + a) * GG
                                     + g * 64 + c0);
        __syncthreads();  // gp ready

        float4 gv0 = *(const float4*)&gp[0][a][c0];
        float4 gv1 = *(const float4*)&gp[1][a][c0];
        float4 gv2 = *(const float4*)&gp[2][a][c0];
        float4 gv3 = *(const float4*)&gp[3][a][c0];
        float hv[4];
        {
            float gi[4] = {gv0.x + bf_lo(gxv[0].x), gv0.y + bf_hi(gxv[0].x),
                           gv0.z + bf_lo(gxv[0].y), gv0.w + bf_hi(gxv[0].y)};
            float gf[4] = {gv1.x + bf_lo(gxv[1].x), gv1.y + bf_hi(gxv[1].x),
                           gv1.z + bf_lo(gxv[1].y), gv1.w + bf_hi(gxv[1].y)};
            float gz[4] = {gv2.x + bf_lo(gxv[2].x), gv2.y + bf_hi(gxv[2].x),
                           gv2.z + bf_lo(gxv[2].y), gv2.w + bf_hi(gxv[2].y)};
            float go[4] = {gv3.x + bf_lo(gxv[3].x), gv3.y + bf_hi(gxv[3].x),
                           gv3.z + bf_lo(gxv[3].y), gv3.w + bf_hi(gxv[3].y)};
            #pragma unroll
            for (int e = 0; e < 4; ++e) {
                float ig = sigm(gi[e]);
                float fg = sigm(gf[e]);
                float zg = tanh_fast(gz[e]);
                float og = sigm(go[e]);
                cst[e] = fmaf(fg, cst[e], ig * zg);
                hv[e] = og * tanh_fast(cst[e]);
            }
        }
        {
            uint2 pk;
            pk.x = pack2(hv[0], hv[1]);
            pk.y = pack2(hv[2], hv[3]);
            *(uint2*)&h_sh[a * 72 + c0] = pk;
        }
        float4 ho; ho.x = hv[0]; ho.y = hv[1]; ho.z = hv[2]; ho.w = hv[3];
        *(float4*)(out + (((size_t)(a0 + a) * TT + t) << 6) + c0) = ho;
        if (t == TT - 1) {
            size_t hb = (size_t)NA * TT * OO;
            *(float4*)(out + hb + ((size_t)(a0 + a) << 6) + c0) = ho;
            float4 co; co.x = cst[0]; co.y = cst[1]; co.z = cst[2]; co.w = cst[3];
            *(float4*)(out + hb + ((size_t)NA << 6) + ((size_t)(a0 + a) << 6) + c0) = co;
        }
        gxv[0] = gxn[0]; gxv[1] = gxn[1]; gxv[2] = gxn[2]; gxv[3] = gxn[3];
    }
}

extern "C" void kernel_launch(void* const* d_in, const int* in_sizes, int n_in,
                              void* d_out, int out_size, void* d_ws, size_t ws_size,
                              hipStream_t stream) {
    const float* x      = (const float*)d_in[0];
    const int*   A      = (const int*)  d_in[1];
    const float* conv_w = (const float*)d_in[2];
    const float* conv_b = (const float*)d_in[3];
    const float* w_ih   = (const float*)d_in[4];
    const float* w_hh   = (const float*)d_in[5];
    const float* b_ih   = (const float*)d_in[6];
    const float* b_hh   = (const float*)d_in[7];
    float* out = (float*)d_out;

    char* ws = (char*)d_ws;
    __hip_bfloat16* P  = (__hip_bfloat16*)ws;                    // 5.25 MB
    size_t offGx = (size_t)TT * NA * OO * 2;
    __hip_bfloat16* gx = (__hip_bfloat16*)(ws + offGx);          // 21 MB
    size_t offW  = offGx + (size_t)TT * NA * GG * 2;
    unsigned short* wihb = (unsigned short*)(ws + offW);         // 32 KB
    unsigned short* whhb = wihb + 4 * OO * OO;                   // 32 KB
    float* biasT = (float*)(whhb + 4 * OO * OO);                 // 1 KB

    // allow 128KB dynamic LDS for gfeat (host-side attr, not captured)
    (void)hipFuncSetAttribute((const void*)gfeat_kernel,
                              hipFuncAttributeMaxDynamicSharedMemorySize,
                              131072);

    hipLaunchKernelGGL(proj_kernel, dim3(NA * TT / 16 + 1), dim3(256), 0, stream,
                       x, conv_w, conv_b, w_ih, w_hh, b_ih, b_hh,
                       P, wihb, whhb, biasT);
    hipLaunchKernelGGL(gfeat_kernel, dim3(TT * 16), dim3(256), 131072, stream,
                       P, A, wihb, biasT, gx);
    hipLaunchKernelGGL(lstm_kernel, dim3(NA / 16), dim3(256), 0, stream,
                       gx, whhb, out);
}

// Round 9
// 139.937 us; speedup vs baseline: 1.3444x; 1.3444x over previous
//
#include <hip/hip_runtime.h>
#include <hip/hip_bf16.h>
#include <math.h>

#define NA 2048   // agents (2^11)
#define TT 20     // timesteps
#define KK 32     // neighbors
#define CC 32     // in channels
#define OO 64     // out channels / hidden
#define GG 256    // 4*OO gates
#define SW 88     // feat_sh row stride in shorts
#define SLABB (17 * 1024)   // bytes of gather slab per wave

typedef __attribute__((ext_vector_type(8))) short short8;
typedef __attribute__((ext_vector_type(4))) float float4v;
typedef __attribute__((ext_vector_type(4))) unsigned uint4v;

__device__ __forceinline__ float fast_rcp(float x) {
    return __builtin_amdgcn_rcpf(x);
}
__device__ __forceinline__ float sigm(float x) {
    return fast_rcp(1.f + __expf(-x));
}
__device__ __forceinline__ float tanh_fast(float x) {
    return 1.f - 2.f * fast_rcp(1.f + __expf(2.f * x));
}
// bf16 RNE on raw bits (ties-to-even; NaN not expected here).
__device__ __forceinline__ unsigned cvt_rne(float f) {
    unsigned u = __float_as_uint(f);
    return (u + 0x7FFFu + ((u >> 16) & 1u)) >> 16;
}
__device__ __forceinline__ unsigned pack2(float a, float b) {
    return cvt_rne(a) | (cvt_rne(b) << 16);
}
__device__ __forceinline__ float bf_lo(unsigned u) {
    return __uint_as_float(u << 16);
}
__device__ __forceinline__ float bf_hi(unsigned u) {
    return __uint_as_float(u & 0xffff0000u);
}
// Async global->LDS, 16B per lane. Dest = wave-uniform base + lane*16.
// No result VGPRs -> compiler cannot cap the outstanding-load depth.
__device__ __forceinline__ void async16(const void* g, void* l) {
    __builtin_amdgcn_global_load_lds(
        (const __attribute__((address_space(1))) unsigned*)g,
        (__attribute__((address_space(3))) unsigned*)l, 16, 0, 0);
}

// P[t][n][o] = sum_c x[n][t][c] * conv_w[o][c], stored bf16 (128B rows).
// Block 0 pre-converts w_ih/w_hh to bf16 and precomputes the folded gate
// bias (b_ih + b_hh + conv_b @ w_ih^T).
__global__ __launch_bounds__(256) void proj_kernel(
    const float* __restrict__ x, const float* __restrict__ conv_w,
    const float* __restrict__ conv_b, const float* __restrict__ w_ih,
    const float* __restrict__ w_hh, const float* __restrict__ b_ih,
    const float* __restrict__ b_hh,
    __hip_bfloat16* __restrict__ P, unsigned short* __restrict__ wihb,
    unsigned short* __restrict__ whhb, float* __restrict__ biasT)
{
    const int tid = threadIdx.x;
    if (blockIdx.x == 0) {   // prep block
        for (int e = tid; e < 4 * OO * OO; e += 256) {
            wihb[e] = (unsigned short)cvt_rne(w_ih[e]);
            whhb[e] = (unsigned short)cvt_rne(w_hh[e]);
        }
        float bj = b_ih[tid] + b_hh[tid];
        #pragma unroll
        for (int o = 0; o < OO; o += 4) {
            float4 cb = *(const float4*)(conv_b + o);
            float4 wr = *(const float4*)(w_ih + (size_t)tid * OO + o);
            bj = fmaf(cb.x, wr.x, bj); bj = fmaf(cb.y, wr.y, bj);
            bj = fmaf(cb.z, wr.z, bj); bj = fmaf(cb.w, wr.w, bj);
        }
        biasT[tid] = bj;
        return;
    }
    const int lane = tid & 63;
    const int wv = tid >> 6;
    float w[CC];
    #pragma unroll
    for (int c = 0; c < CC; c += 4) {
        float4 v = *(const float4*)(conv_w + lane * CC + c);
        w[c] = v.x; w[c + 1] = v.y; w[c + 2] = v.z; w[c + 3] = v.w;
    }
    const int rbase = (blockIdx.x - 1) * 16 + wv * 4;
    #pragma unroll
    for (int i = 0; i < 4; ++i) {
        int r = rbase + i;                    // r = n*TT + t (x row order)
        const float* xr = x + (size_t)r * CC;
        float a0 = 0.f, a1 = 0.f;
        #pragma unroll
        for (int c = 0; c < CC; c += 8) {
            float4 v = *(const float4*)(xr + c);
            float4 u = *(const float4*)(xr + c + 4);
            a0 = fmaf(v.x, w[c], a0);     a0 = fmaf(v.y, w[c + 1], a0);
            a0 = fmaf(v.z, w[c + 2], a0); a0 = fmaf(v.w, w[c + 3], a0);
            a1 = fmaf(u.x, w[c + 4], a1); a1 = fmaf(u.y, w[c + 5], a1);
            a1 = fmaf(u.z, w[c + 6], a1); a1 = fmaf(u.w, w[c + 7], a1);
        }
        int n = r / TT;
        int t = r - n * TT;
        ((unsigned short*)P)[(((size_t)t << 11) + n) * OO + lane] =
            (unsigned short)cvt_rne(a0 + a1);
    }
}

// Gather-max + gate MFMA, async-LDS-gather edition.
// R5/R6: VGPR-result gathers were capped at ~2-4 outstanding by the
// register allocator -> latency-bound 53us. R8: shared slab had 8-way bank
// conflicts + 1 block/CU. Here each wave issues 17 global_load_lds dwordx4
// (16 neighbors + self) into a PRIVATE 17KB slab: no result VGPRs, so 17
// outstanding/wave x 8 waves/CU = 136 in flight; consumption is lane-linear
// ds_read_b128 (conflict-free).
__global__ __launch_bounds__(256, 2) void gatemm_kernel(
    const __hip_bfloat16* __restrict__ P, const int* __restrict__ A,
    const unsigned short* __restrict__ wihb, const float* __restrict__ biasT,
    __hip_bfloat16* __restrict__ gx)
{
    extern __shared__ __align__(16) char slab_raw[];         // 4 * 17KB
    __shared__ __align__(16) unsigned short feat_sh[16 * SW];
    __shared__ __align__(8) int A_sh[16 * KK];

    const int tid = threadIdx.x;
    const int lane = tid & 63;
    const int wv = tid >> 6;
    const int l15 = lane & 15;
    const int q = lane >> 4;

    const int bs = (blockIdx.x & 7) * 320 + (blockIdx.x >> 3);  // XCD swizzle
    const int r0 = bs << 4;                  // first row, r = t*NA + n
    const int t = r0 >> 11;
    const int n0 = r0 & (NA - 1);
    const unsigned short* Pb = (const unsigned short*)P + ((size_t)t << 17);

    // Stage A rows coalesced; tid->row mapping keeps each wave's 4 rows
    // written by that same wave (wave-local, no barrier needed).
    ((int2*)A_sh)[tid] = ((const int2*)(A + ((size_t)r0 << 5)))[tid];

    const int i_row = lane >> 4;        // 0..3: which of the wave's 4 rows
    const int ko2   = (lane >> 3) & 1;  // neighbor parity
    const int oc    = lane & 7;         // channel oct (8 bf16 = 16B)

    // Preload all 16 indices (independent ds_reads, one latency).
    int ai[16];
    const int abase = (wv * 4 + i_row) * KK + ko2;
    #pragma unroll
    for (int g = 0; g < 16; ++g) ai[g] = A_sh[abase + 2 * g];

    // Issue 17 async gathers back-to-back into the wave-private slab.
    char* myslab = slab_raw + wv * SLABB;
    #pragma unroll
    for (int g = 0; g < 16; ++g)
        async16(Pb + ((size_t)ai[g] << 6) + oc * 8, myslab + g * 1024);
    async16(Pb + ((size_t)(n0 + wv * 4 + i_row) << 6) + oc * 8,
            myslab + 16 * 1024);

    // Overlap: B-fragments + bias while gathers are in flight.
    float bv[4];
    short8 bfrag[4][2];
    #pragma unroll
    for (int tt2 = 0; tt2 < 4; ++tt2) {
        int j = wv * 64 + tt2 * 16 + l15;
        bv[tt2] = biasT[j];
        #pragma unroll
        for (int ks = 0; ks < 2; ++ks)
            bfrag[tt2][ks] =
                *(const short8*)(wihb + ((size_t)j << 6) + ks * 32 + q * 8);
    }

    __builtin_amdgcn_s_waitcnt(0x0F70);   // vmcnt(0): slab complete

    // Max-reduce: lane-linear ds_read_b128 (slot g at +g*1024 + lane*16).
    const unsigned short* ms = (const unsigned short*)myslab;
    float mx[8];
    #pragma unroll
    for (int e = 0; e < 8; ++e) mx[e] = -INFINITY;
    #pragma unroll
    for (int g = 0; g < 16; ++g) {
        uint4v v = *(const uint4v*)(ms + g * 512 + lane * 8);
        mx[0] = fmaxf(mx[0], bf_lo(v[0])); mx[1] = fmaxf(mx[1], bf_hi(v[0]));
        mx[2] = fmaxf(mx[2], bf_lo(v[1])); mx[3] = fmaxf(mx[3], bf_hi(v[1]));
        mx[4] = fmaxf(mx[4], bf_lo(v[2])); mx[5] = fmaxf(mx[5], bf_hi(v[2]));
        mx[6] = fmaxf(mx[6], bf_lo(v[3])); mx[7] = fmaxf(mx[7], bf_hi(v[3]));
    }
    #pragma unroll
    for (int e = 0; e < 8; ++e)
        mx[e] = fmaxf(mx[e], __shfl_xor(mx[e], 8, 64));  // combine parities

    {
        uint4v sv = *(const uint4v*)(ms + 16 * 512 + lane * 8);  // self
        if (ko2 == 0) {
            uint4v pk;
            pk[0] = pack2(mx[0] - bf_lo(sv[0]), mx[1] - bf_hi(sv[0]));
            pk[1] = pack2(mx[2] - bf_lo(sv[1]), mx[3] - bf_hi(sv[1]));
            pk[2] = pack2(mx[4] - bf_lo(sv[2]), mx[5] - bf_hi(sv[2]));
            pk[3] = pack2(mx[6] - bf_lo(sv[3]), mx[7] - bf_hi(sv[3]));
            *(uint4v*)&feat_sh[(wv * 4 + i_row) * SW + oc * 8] = pk;
        }
    }
    __syncthreads();

    // Gate MFMA: D[16 rows][wave's 64 cols], K=64 in 2 steps.
    float4v acc[4] = {{0.f, 0.f, 0.f, 0.f}, {0.f, 0.f, 0.f, 0.f},
                      {0.f, 0.f, 0.f, 0.f}, {0.f, 0.f, 0.f, 0.f}};
    #pragma unroll
    for (int ks = 0; ks < 2; ++ks) {
        short8 af = *(const short8*)(&feat_sh[l15 * SW + ks * 32 + q * 8]);
        #pragma unroll
        for (int tt2 = 0; tt2 < 4; ++tt2)
            acc[tt2] = __builtin_amdgcn_mfma_f32_16x16x32_bf16(
                af, bfrag[tt2][ks], acc[tt2], 0, 0, 0);
    }

    // D: row m = q*4+rg, col j = wv*64 + tt2*16 + l15
    #pragma unroll
    for (int tt2 = 0; tt2 < 4; ++tt2) {
        int j = wv * 64 + tt2 * 16 + l15;
        #pragma unroll
        for (int rg = 0; rg < 4; ++rg)
            gx[((size_t)(r0 + q * 4 + rg) << 8) + j] =
                __float2bfloat16(__uint_as_float(
                    cvt_rne(acc[tt2][rg] + bv[tt2]) << 16));
    }
}

// Serial recurrence via MFMA: 16 agents/block (128 blocks), R5 structure.
__global__ __launch_bounds__(256, 4) void lstm_kernel(
    const __hip_bfloat16* __restrict__ gx, const unsigned short* __restrict__ whhb,
    float* __restrict__ out)
{
    const int tid = threadIdx.x;
    const int lane = tid & 63;
    const int wv = tid >> 6;          // gate plane
    const int l15 = lane & 15;
    const int q = lane >> 4;
    const int a0 = blockIdx.x * 16;
    const int a = tid >> 4;           // pointwise: agent 0..15
    const int c0 = (tid & 15) * 4;    // pointwise: first channel

    // B-frags from preconverted bf16: B[k][ch] = w_hh[wv*64 + ch][k]
    short8 bfrag[4][2];
    #pragma unroll
    for (int tt2 = 0; tt2 < 4; ++tt2) {
        int row = wv * 64 + tt2 * 16 + l15;
        #pragma unroll
        for (int ks = 0; ks < 2; ++ks)
            bfrag[tt2][ks] =
                *(const short8*)(whhb + ((size_t)row << 6) + ks * 32 + q * 8);
    }

    __shared__ __align__(16) unsigned short h_sh[16 * 72];  // bf16, pad 72
    __shared__ float gp[4][16][68];                         // gate planes

    {   // h = 0
        uint2 z; z.x = 0u; z.y = 0u;
        *(uint2*)&h_sh[a * 72 + c0] = z;
    }
    float cst[4] = {0.f, 0.f, 0.f, 0.f};

    const unsigned short* gxp = (const unsigned short*)gx;
    uint2 gxv[4];
    #pragma unroll
    for (int g = 0; g < 4; ++g)
        gxv[g] = *(const uint2*)(gxp + ((size_t)(a0 + a) << 8) + g * 64 + c0);

    for (int t = 0; t < TT; ++t) {
        __syncthreads();  // h_sh ready (init or previous pointwise)

        float4v acc[4] = {{0.f, 0.f, 0.f, 0.f}, {0.f, 0.f, 0.f, 0.f},
                          {0.f, 0.f, 0.f, 0.f}, {0.f, 0.f, 0.f, 0.f}};
        #pragma unroll
        for (int ks = 0; ks < 2; ++ks) {
            short8 af = *(const short8*)(&h_sh[l15 * 72 + ks * 32 + q * 8]);
            #pragma unroll
            for (int tt2 = 0; tt2 < 4; ++tt2)
                acc[tt2] = __builtin_amdgcn_mfma_f32_16x16x32_bf16(
                    af, bfrag[tt2][ks], acc[tt2], 0, 0, 0);
        }
        #pragma unroll
        for (int tt2 = 0; tt2 < 4; ++tt2)
            #pragma unroll
            for (int rg = 0; rg < 4; ++rg)
                gp[wv][q * 4 + rg][tt2 * 16 + l15] = acc[tt2][rg];

        // prefetch next step's gx while gp settles
        uint2 gxn[4];
        int tn = (t + 1 < TT) ? t + 1 : t;
        #pragma unroll
        for (int g = 0; g < 4; ++g)
            gxn[g] = *(const uint2*)(gxp + (((size_t)tn << 11) + a0 + a) * GG
                                     + g * 64 + c0);
        __syncthreads();  // gp ready

        float4 gv0 = *(const float4*)&gp[0][a][c0];
        float4 gv1 = *(const float4*)&gp[1][a][c0];
        float4 gv2 = *(const float4*)&gp[2][a][c0];
        float4 gv3 = *(const float4*)&gp[3][a][c0];
        float hv[4];
        {
            float gi[4] = {gv0.x + bf_lo(gxv[0].x), gv0.y + bf_hi(gxv[0].x),
                           gv0.z + bf_lo(gxv[0].y), gv0.w + bf_hi(gxv[0].y)};
            float gf[4] = {gv1.x + bf_lo(gxv[1].x), gv1.y + bf_hi(gxv[1].x),
                           gv1.z + bf_lo(gxv[1].y), gv1.w + bf_hi(gxv[1].y)};
            float gz[4] = {gv2.x + bf_lo(gxv[2].x), gv2.y + bf_hi(gxv[2].x),
                           gv2.z + bf_lo(gxv[2].y), gv2.w + bf_hi(gxv[2].y)};
            float go[4] = {gv3.x + bf_lo(gxv[3].x), gv3.y + bf_hi(gxv[3].x),
                           gv3.z + bf_lo(gxv[3].y), gv3.w + bf_hi(gxv[3].y)};
            #pragma unroll
            for (int e = 0; e < 4; ++e) {
                float ig = sigm(gi[e]);
                float fg = sigm(gf[e]);
                float zg = tanh_fast(gz[e]);
                float og = sigm(go[e]);
                cst[e] = fmaf(fg, cst[e], ig * zg);
                hv[e] = og * tanh_fast(cst[e]);
            }
        }
        {
            uint2 pk;
            pk.x = pack2(hv[0], hv[1]);
            pk.y = pack2(hv[2], hv[3]);
            *(uint2*)&h_sh[a * 72 + c0] = pk;
        }
        float4 ho; ho.x = hv[0]; ho.y = hv[1]; ho.z = hv[2]; ho.w = hv[3];
        *(float4*)(out + (((size_t)(a0 + a) * TT + t) << 6) + c0) = ho;
        if (t == TT - 1) {
            size_t hb = (size_t)NA * TT * OO;
            *(float4*)(out + hb + ((size_t)(a0 + a) << 6) + c0) = ho;
            float4 co; co.x = cst[0]; co.y = cst[1]; co.z = cst[2]; co.w = cst[3];
            *(float4*)(out + hb + ((size_t)NA << 6) + ((size_t)(a0 + a) << 6) + c0) = co;
        }
        gxv[0] = gxn[0]; gxv[1] = gxn[1]; gxv[2] = gxn[2]; gxv[3] = gxn[3];
    }
}

extern "C" void kernel_launch(void* const* d_in, const int* in_sizes, int n_in,
                              void* d_out, int out_size, void* d_ws, size_t ws_size,
                              hipStream_t stream) {
    const float* x      = (const float*)d_in[0];
    const int*   A      = (const int*)  d_in[1];
    const float* conv_w = (const float*)d_in[2];
    const float* conv_b = (const float*)d_in[3];
    const float* w_ih   = (const float*)d_in[4];
    const float* w_hh   = (const float*)d_in[5];
    const float* b_ih   = (const float*)d_in[6];
    const float* b_hh   = (const float*)d_in[7];
    float* out = (float*)d_out;

    char* ws = (char*)d_ws;
    __hip_bfloat16* P  = (__hip_bfloat16*)ws;                    // 5.25 MB
    size_t offGx = (size_t)TT * NA * OO * 2;
    __hip_bfloat16* gx = (__hip_bfloat16*)(ws + offGx);          // 21 MB
    size_t offW  = offGx + (size_t)TT * NA * GG * 2;
    unsigned short* wihb = (unsigned short*)(ws + offW);         // 32 KB
    unsigned short* whhb = wihb + 4 * OO * OO;                   // 32 KB
    float* biasT = (float*)(whhb + 4 * OO * OO);                 // 1 KB

    // 68KB dynamic LDS for the gather slabs (host-side attr, capture-safe
    // per R8 evidence).
    (void)hipFuncSetAttribute((const void*)gatemm_kernel,
                              hipFuncAttributeMaxDynamicSharedMemorySize,
                              4 * SLABB);

    hipLaunchKernelGGL(proj_kernel, dim3(NA * TT / 16 + 1), dim3(256), 0, stream,
                       x, conv_w, conv_b, w_ih, w_hh, b_ih, b_hh,
                       P, wihb, whhb, biasT);
    hipLaunchKernelGGL(gatemm_kernel, dim3(NA * TT / 16), dim3(256), 4 * SLABB,
                       stream, P, A, wihb, biasT, gx);
    hipLaunchKernelGGL(lstm_kernel, dim3(NA / 16), dim3(256), 0, stream,
                       gx, whhb, out);
}